// Round 4
// baseline (86.992 us; speedup 1.0000x reference)
//
#include <hip/hip_runtime.h>
#include <hip/hip_fp16.h>

#define B 128
#define L 1024

#if __has_builtin(__builtin_amdgcn_exp2f)
#define EXP2(x) __builtin_amdgcn_exp2f(x)
#else
#define EXP2(x) __expf((x) * 0.6931471805599453f)
#endif

typedef unsigned int uint4v __attribute__((ext_vector_type(4)));
typedef float f32x2 __attribute__((ext_vector_type(2)));

// ws layout (floats):
//   [0..2048)  per-block dcg partials: idx = b*16 + iseg
//   [2048]     ndcg accumulator      (zeroed by pair_kernel block 0)
//   [2049]     completion counter    (zeroed by pair_kernel block 0)
#define WS_ACC  2048
#define WS_GCTR 2049

// erfc(|y|) ~= exp(-(1.12838 y + 0.6446 y^2 + 0.0745 y^3)), |dPhi| <= ~2.5e-4,
// y = diff/2 (prescaled into the f16 row). Constants pre-multiplied by
// -log2(e) so v_exp_f16 computes exp2 directly.
#define K1f -1.6279072f
#define K2f -0.9299637f
#define K3f -0.1074808f

// one packed evaluation: du holds 2 f16 j-values; acc += erf(y_i - y_j) x2.
// R15: exp via hexp2 intrinsics (R14's op_sel:[1,1] asm does NOT assemble on
// gfx950 — VOP3 f16 VOP1 ops have no op_sel there; the lshr/exp/exp/pack the
// compiler emits is the legal floor). Kept: v_bfi sign transfer (1 op vs
// and+or) and packed-f32 window flush.
__device__ __forceinline__ void term2(unsigned int du, __half2 pi2,
                                      __half2 k1, __half2 k2, __half2 k3,
                                      __half2 one2, __half2& acc) {
    __half2 pj = __builtin_bit_cast(__half2, du);
    __half2 d  = __hsub2(pi2, pj);
    unsigned int dbits = __builtin_bit_cast(unsigned int, d);
    __half2 a  = __builtin_bit_cast(__half2, dbits & 0x7fff7fffu); // |d| both halves
    __half2 t  = __hfma2(k3, a, k2);
    __half2 u  = __hfma2(t,  a, k1);
    __half2 w  = __hmul2(a, u);                      // <= 0
    __half2 e  = __halves2half2(hexp2(__low2half(w)),
                                hexp2(__high2half(w)));   // ~= erfc(|y|)
    __half2 r  = __hsub2(one2, e);                   // >= 0, sign bits clear
    // canonical bfi pattern: (d & mask) | (r & ~mask) -> v_bfi_b32
    unsigned int rs = (dbits & 0x80008000u)
                    | (__builtin_bit_cast(unsigned int, r) & 0x7fff7fffu);
    acc = __hadd2(acc, __builtin_bit_cast(__half2, rs));  // erf(y), signed
}

__device__ __forceinline__ f32x2 h2f(__half2 h) {
    float2 f = __half22float2(h);
    f32x2 r; r.x = f.x; r.y = f.y;
    return r;
}

// grid = B*16 = 2048 blocks, 256 threads -> 8 blocks/CU -> 32 waves/CU (HW
// max; R13's 1024 blocks gave only 16 and ~55% issue efficiency on the exp
// dep-chains). Block (b, iseg) owns 64 i's; thread (il = tid&63, jq = tid>>6)
// sums its 256-j quarter from the 2KB f16 LDS row with 8 independent half2
// accumulator chains (f32 flush every window; |acc|<=8 so f16 rounding is
// negligible). j-pointer is wave-uniform. NO global atomics/fences here
// (R6 lesson); one plain partial store per block.
__global__ __launch_bounds__(256, 8) void pair_kernel(const float* __restrict__ preds,
                                                      const float* __restrict__ target,
                                                      float* __restrict__ ws) {
    __shared__ __align__(16) __half sph[L];   // row * 0.5, f16
    __shared__ float red[256];                // cross-quarter E reduction

    const int blk  = blockIdx.x;
    const int b    = blk >> 4;
    const int iseg = blk & 15;
    const int tid  = threadIdx.x;
    const int il   = tid & 63;                // i_lane
    const int jq   = tid >> 6;                // j quarter (0..3) == wave id

    if (blk == 0 && tid == 0) {
        ws[WS_ACC] = 0.0f;                    // visible to finish_kernel at
        ((int*)ws)[WS_GCTR] = 0;              // dispatch boundary
    }

    const float* prow = preds + b * L;

    // stage row as f16, prescaled by 0.5 (erf argument is diff/2)
    float4 v4 = reinterpret_cast<const float4*>(prow)[tid];
    __half2 h01 = __floats2half2_rn(0.5f * v4.x, 0.5f * v4.y);
    __half2 h23 = __floats2half2_rn(0.5f * v4.z, 0.5f * v4.w);
    reinterpret_cast<__half2*>(sph)[tid * 2 + 0] = h01;
    reinterpret_cast<__half2*>(sph)[tid * 2 + 1] = h23;

    const int i = iseg * 64 + il;
    const float tgt = (tid < 64) ? target[b * L + iseg * 64 + tid] : 0.0f;

    __syncthreads();

    const __half2 pi2  = __half2half2(sph[i]);
    const __half2 k1   = __floats2half2_rn(K1f, K1f);
    const __half2 k2   = __floats2half2_rn(K2f, K2f);
    const __half2 k3   = __floats2half2_rn(K3f, K3f);
    const __half2 one2 = __floats2half2_rn(1.0f, 1.0f);
    const __half2 z2   = __floats2half2_rn(0.0f, 0.0f);

    // this wave's j-quarter: 256 f16 = 32 uint4 (each uint4 = 8 terms)
    const uint4v* basep = reinterpret_cast<const uint4v*>(sph + jq * 256);

    float E = 0.0f;
    for (int wdw = 0; wdw < 2; ++wdw) {       // 2 windows x 128 terms
        __half2 A0 = z2, A1 = z2, A2 = z2, A3 = z2,
                A4 = z2, A5 = z2, A6 = z2, A7 = z2;
        #pragma unroll
        for (int m = 0; m < 8; ++m) {         // 2 uint4 per step, 8 chains
            uint4v q0 = basep[wdw * 16 + m * 2 + 0];
            uint4v q1 = basep[wdw * 16 + m * 2 + 1];
            term2(q0.x, pi2, k1, k2, k3, one2, A0);
            term2(q0.y, pi2, k1, k2, k3, one2, A1);
            term2(q0.z, pi2, k1, k2, k3, one2, A2);
            term2(q0.w, pi2, k1, k2, k3, one2, A3);
            term2(q1.x, pi2, k1, k2, k3, one2, A4);
            term2(q1.y, pi2, k1, k2, k3, one2, A5);
            term2(q1.z, pi2, k1, k2, k3, one2, A6);
            term2(q1.w, pi2, k1, k2, k3, one2, A7);
        }
        // packed-f32 flush: v_pk_add_f32 tree (7 pk adds) vs 15 scalar adds
        f32x2 s01 = (h2f(A0) + h2f(A1)) + (h2f(A2) + h2f(A3));
        f32x2 s45 = (h2f(A4) + h2f(A5)) + (h2f(A6) + h2f(A7));
        f32x2 s   = s01 + s45;
        E += s.x + s.y;
    }

    // cross-quarter combine in LDS; wave 0 finishes the 64 i's
    red[tid] = E;
    __syncthreads();

    if (tid < 64) {
        float Es = (red[tid] + red[tid + 64]) + (red[tid + 128] + red[tid + 192]);
        // sum_j Phi = L/2 + Es/2 (diag term is exactly 0); er+1 = 513.5 + Es/2
        float er1 = 513.5f + 0.5f * Es;
        float g = EXP2(tgt) - 1.0f;           // 2^t - 1, exact for integer grades
        float contrib = g * __builtin_amdgcn_rcpf(__log2f(er1));
        #pragma unroll
        for (int off = 32; off > 0; off >>= 1)
            contrib += __shfl_down(contrib, off);
        if (tid == 0)
            ws[blk] = contrib;                // plain store, disjoint slot
    }
}

// grid = B blocks, 256 threads. Block b: combine 16 dcg partials, counting-sort
// IDCG (grades are ints 0..4), ndcg; last block writes the final scalar.
__global__ __launch_bounds__(256) void finish_kernel(const float* __restrict__ target,
                                                     float* __restrict__ ws,
                                                     float* __restrict__ out) {
    __shared__ unsigned long long cred[256];
    __shared__ float2 fred[256];

    const int b   = blockIdx.x;
    const int tid = threadIdx.x;
    const float* trow = target + b * L;

    // packed 16-bit counts of grades >=4,>=3,>=2,>=1 (max 1024 fits)
    unsigned long long cnt = 0ull;
    #pragma unroll
    for (int k = 0; k < 4; ++k) {
        float t = trow[tid + k * 256];
        cnt += ((unsigned long long)(t > 3.5f) << 48)
             + ((unsigned long long)(t > 2.5f) << 32)
             + ((unsigned long long)(t > 1.5f) << 16)
             + ((unsigned long long)(t > 0.5f));
    }
    cred[tid] = cnt;
    __syncthreads();
    #pragma unroll
    for (int s = 128; s > 0; s >>= 1) {
        if (tid < (unsigned)s) cred[tid] += cred[tid + s];
        __syncthreads();
    }
    unsigned long long tot = cred[0];
    const int n4 = (int)(tot >> 48) & 0xFFFF;
    const int n3 = (int)(tot >> 32) & 0xFFFF;
    const int n2 = (int)(tot >> 16) & 0xFFFF;
    const int n1 = (int)(tot)       & 0xFFFF;

    // parallel IDCG; joint reduction with the 16 dcg partials of this row
    float idcg_p = 0.0f;
    #pragma unroll
    for (int k = 0; k < 4; ++k) {
        int pos = tid + 1 + k * 256;
        float gain = (pos <= n4) ? 15.0f : (pos <= n3) ? 7.0f :
                     (pos <= n2) ? 3.0f  : (pos <= n1) ? 1.0f : 0.0f;
        idcg_p += gain * __builtin_amdgcn_rcpf(__log2f((float)pos + 1.0f));
    }
    float dcg_p = (tid < 16) ? ws[b * 16 + tid] : 0.0f;
    fred[tid] = make_float2(idcg_p, dcg_p);
    __syncthreads();
    #pragma unroll
    for (int s = 128; s > 0; s >>= 1) {
        if (tid < (unsigned)s) {
            float2 x = fred[tid], y = fred[tid + s];
            fred[tid] = make_float2(x.x + y.x, x.y + y.y);
        }
        __syncthreads();
    }

    if (tid == 0) {
        float ndcg = fred[0].y / (fred[0].x + 1e-10f);
        atomicAdd(&ws[WS_ACC], ndcg);
        __threadfence();
        int old = atomicAdd((int*)ws + WS_GCTR, 1);
        if (old == B - 1) {
            float acc = atomicAdd(&ws[WS_ACC], 0.0f);  // coherent read
            out[0] = -acc * (1.0f / (float)B);
        }
    }
}

extern "C" void kernel_launch(void* const* d_in, const int* in_sizes, int n_in,
                              void* d_out, int out_size, void* d_ws, size_t ws_size,
                              hipStream_t stream) {
    const float* preds  = (const float*)d_in[0];
    const float* target = (const float*)d_in[1];
    float* out = (float*)d_out;
    float* ws  = (float*)d_ws;

    pair_kernel<<<B * 16, 256, 0, stream>>>(preds, target, ws);
    finish_kernel<<<B, 256, 0, stream>>>(target, ws, out);
}